// Round 7
// baseline (125.285 us; speedup 1.0000x reference)
//
#include <hip/hip_runtime.h>

typedef __bf16 bf16x8 __attribute__((ext_vector_type(8)));
typedef __bf16 bf16x4 __attribute__((ext_vector_type(4)));
typedef float  f32x4  __attribute__((ext_vector_type(4)));

#define LOG2E_F 1.44269504088896340736f

static constexpr int kB = 2, kN = 2048, kH = 8, kD = 64, kDim = 512;
static constexpr int kTok = kB * kN;   // 4096
static constexpr int kNQKV = 1536;     // fused Wq(512)+Wkv(1024) rows
static constexpr int kKH = 3;          // attention split-K: 11/11/10 kt tiles

__device__ __forceinline__ void gld16(const void* g, void* l) {
  __builtin_amdgcn_global_load_lds(
      (const __attribute__((address_space(1))) void*)g,
      (__attribute__((address_space(3))) void*)l, 16, 0, 0);
}

// XOR-swizzled LDS tiles (rows of 64 bf16 = 8 chunks of 16B):
// LDS chunk c of row r holds GLOBAL chunk c^(r&7). Staged via per-lane source
// permutation (gld16 dest stays lane-linear); readers XOR their chunk index
// with (row&7). Spreads quad-group b128 reads over all 32 banks.

// ===== fp32 -> bf16 linear converts: x | Wq | Wkv (fused) | Wout ===========
__global__ __launch_bounds__(256) void cvt_all(const float* __restrict__ x,
                                               const float* __restrict__ wq,
                                               const float* __restrict__ wkv,
                                               const float* __restrict__ wo,
                                               __bf16* __restrict__ xb,
                                               __bf16* __restrict__ wqkvb,
                                               __bf16* __restrict__ wob) {
  size_t i = ((size_t)blockIdx.x * 256 + threadIdx.x) * 8;
  const float* s; __bf16* d; size_t off;
  if (i < 2097152)      { s = x;   d = xb;              off = i; }
  else if (i < 2359296) { s = wq;  d = wqkvb;           off = i - 2097152; }
  else if (i < 2883584) { s = wkv; d = wqkvb + 262144;  off = i - 2359296; }
  else                  { s = wo;  d = wob;             off = i - 2883584; }
  float4 u = *(const float4*)(s + off);
  float4 v = *(const float4*)(s + off + 4);
  bf16x8 t;
  t[0] = (__bf16)u.x; t[1] = (__bf16)u.y; t[2] = (__bf16)u.z; t[3] = (__bf16)u.w;
  t[4] = (__bf16)v.x; t[5] = (__bf16)v.y; t[6] = (__bf16)v.z; t[7] = (__bf16)v.w;
  *(bf16x8*)(d + off) = t;
}

// ===== QKV GEMM with fused norm/transpose epilogue =========================
__global__ __launch_bounds__(256, 3) void gemm_qkv(const __bf16* __restrict__ A,
                                                   const __bf16* __restrict__ B,
                                                   __bf16* __restrict__ qn,
                                                   __bf16* __restrict__ kn,
                                                   __bf16* __restrict__ vt2) {
  const int K = kDim;
  const int tid = threadIdx.x;
  const int w = tid >> 6, lane = tid & 63, quad = lane >> 4, lq = lane & 15;
  const int m0 = blockIdx.y * 128;
  const int n0 = blockIdx.x * 64;
  const int wm = w * 32;
  __shared__ __bf16 As[2][128 * 64];
  __shared__ __bf16 Bs[2][64 * 64];

  const f32x4 zero = {0.f, 0.f, 0.f, 0.f};
  f32x4 acc[2][4];
#pragma unroll
  for (int fm = 0; fm < 2; ++fm)
#pragma unroll
    for (int fn = 0; fn < 4; ++fn) acc[fm][fn] = zero;

  const int sr = tid >> 3, ch = tid & 7;
  auto stage = [&](int k0, int buf) {
#pragma unroll
    for (int j = 0; j < 4; ++j) {
      const int row = j * 32 + sr;
      gld16(A + (size_t)(m0 + row) * K + k0 + ((ch ^ (row & 7)) << 3),
            &As[buf][row * 64 + ch * 8]);
    }
#pragma unroll
    for (int j = 0; j < 2; ++j) {
      const int row = j * 32 + sr;
      gld16(B + (size_t)(n0 + row) * K + k0 + ((ch ^ (row & 7)) << 3),
            &Bs[buf][row * 64 + ch * 8]);
    }
  };
  const int sw0 = ((quad ^ (lq & 7)) << 3);        // ks=0
  const int sw1 = (((4 | quad) ^ (lq & 7)) << 3);  // ks=1

  stage(0, 0);
  for (int i = 0; i < 8; ++i) {
    __syncthreads();
    if (i + 1 < 8) stage((i + 1) << 6, (i + 1) & 1);
    const __bf16* as = As[i & 1];
    const __bf16* bs = Bs[i & 1];
#pragma unroll
    for (int ks = 0; ks < 2; ++ks) {
      const int sw = ks ? sw1 : sw0;
      bf16x8 a[2], b[4];
#pragma unroll
      for (int fm = 0; fm < 2; ++fm)
        a[fm] = *(const bf16x8*)&as[(wm + fm * 16 + lq) * 64 + sw];
#pragma unroll
      for (int fn = 0; fn < 4; ++fn)
        b[fn] = *(const bf16x8*)&bs[(fn * 16 + lq) * 64 + sw];
#pragma unroll
      for (int fm = 0; fm < 2; ++fm)
#pragma unroll
        for (int fn = 0; fn < 4; ++fn)
          acc[fm][fn] =
              __builtin_amdgcn_mfma_f32_16x16x32_bf16(a[fm], b[fn], acc[fm][fn], 0, 0, 0);
    }
  }

  const int h = (n0 >> 6) & 7;
  if (n0 >= 1024) {
    // ---- V: transpose via LDS (reuse As), then coalesced 16B stores ----
    __syncthreads();
    __bf16* Ts = &As[0][0];  // [2 tiles][64 d][stride 72]
#pragma unroll
    for (int fm = 0; fm < 2; ++fm)
#pragma unroll
      for (int r = 0; r < 4; ++r) {
        const int mo = wm + fm * 16 + quad * 4 + r;
        const int tau = mo >> 6, tt = mo & 63;
        const int p = (tt & 15) * 4 + (tt >> 4);  // inverse of attn's pi
#pragma unroll
        for (int fn = 0; fn < 4; ++fn)
          Ts[tau * 4608 + (fn * 16 + lq) * 72 + p] = (__bf16)acc[fm][fn][r];
      }
    __syncthreads();
    const int b = m0 >> 11, kt0 = (m0 & (kN - 1)) >> 6;
    const int dd = tid >> 2, p0 = (tid & 3) << 4;
#pragma unroll
    for (int tau = 0; tau < 2; ++tau) {
      const __bf16* src = Ts + tau * 4608 + dd * 72 + p0;
      __bf16* dst = vt2 + ((size_t)((b * kH + h) * 32 + kt0 + tau)) * 4096 + tid * 16;
      *(bf16x8*)dst = *(const bf16x8*)src;
      *(bf16x8*)(dst + 8) = *(const bf16x8*)(src + 8);
    }
  } else {
    // ---- Q/K: rms over the 64 cols ----
    const float qs = (n0 < 512) ? (0.125f * LOG2E_F) : 1.0f;
    __bf16* dst0 = (n0 < 512) ? qn : kn;
#pragma unroll
    for (int fm = 0; fm < 2; ++fm)
#pragma unroll
      for (int r = 0; r < 4; ++r) {
        float ss = 0.f;
#pragma unroll
        for (int fn = 0; fn < 4; ++fn) ss += acc[fm][fn][r] * acc[fm][fn][r];
#pragma unroll
        for (int off = 1; off < 16; off <<= 1) ss += __shfl_xor(ss, off, 64);
        const float inv = qs / (sqrtf(ss * (1.f / 64)) + 1e-4f);
        const int m = m0 + wm + fm * 16 + quad * 4 + r;
        const int b = m >> 11, n = m & (kN - 1);
        __bf16* dst = dst0 + ((size_t)(b * kH + h) * kN + n) * kD;
#pragma unroll
        for (int fn = 0; fn < 4; ++fn)
          dst[fn * 16 + lq] = (__bf16)(acc[fm][fn][r] * inv);
      }
  }
}

// ===== fused attention: block = (128-q tile, bh, key-third) ================
// EXACT verified baseline structure (split-K3, Ps-LDS softmax, no setprio).
// Fixed-max softmax (|s| <= 11.54 < 12; bias -12 in MFMA C-init).
__global__ __launch_bounds__(256, 3) void attn(const __bf16* __restrict__ qn,
                                               const __bf16* __restrict__ kn,
                                               const __bf16* __restrict__ vt2,
                                               __bf16* __restrict__ po,
                                               float* __restrict__ pl) {
  const int qt = blockIdx.x, bh = blockIdx.y, kh = blockIdx.z;
  const int kt0 = kh * 11;
  const int cnt = (kh == 2) ? 10 : 11;
  const int tid = threadIdx.x;
  const int w = tid >> 6, lane = tid & 63, quad = lane >> 4, lq = lane & 15;
  __shared__ __bf16 Ks[2][4096];
  __shared__ __bf16 Vs[2][4096];
  __shared__ __bf16 Ps[4][32 * 72];
  __bf16* myP = Ps[w];

  bf16x8 aq[2][2];
#pragma unroll
  for (int fm = 0; fm < 2; ++fm) {
    const __bf16* Qb = qn + ((size_t)bh * kN + qt * 128 + w * 32 + fm * 16 + lq) * kD;
    aq[fm][0] = *(const bf16x8*)(Qb + quad * 8);
    aq[fm][1] = *(const bf16x8*)(Qb + 32 + quad * 8);
  }

  const f32x4 zero  = {0.f, 0.f, 0.f, 0.f};
  const f32x4 minit = {-12.f, -12.f, -12.f, -12.f};
  f32x4 o[2][4];
  float lr[2][4];
#pragma unroll
  for (int fm = 0; fm < 2; ++fm)
#pragma unroll
    for (int i = 0; i < 4; ++i) { o[fm][i] = zero; lr[fm][i] = 0.f; }

  const __bf16* Kb = kn + (size_t)bh * kN * kD;   // tile ktg at +ktg*4096
  const __bf16* Vb = vt2 + (size_t)bh * 32 * 4096;

  auto stage = [&](int ktg, int buf) {
#pragma unroll
    for (int j = 0; j < 2; ++j) {
      const int s = j * 256 + tid;
      const int row = s >> 3, ch = s & 7;
      const int src = row * 64 + ((ch ^ (row & 7)) << 3);
      gld16(Kb + (size_t)ktg * 4096 + src, &Ks[buf][s * 8]);
      gld16(Vb + (size_t)ktg * 4096 + src, &Vs[buf][s * 8]);
    }
  };
  const int sw0 = ((quad ^ (lq & 7)) << 3);
  const int sw1 = (((4 | quad) ^ (lq & 7)) << 3);

  stage(kt0, 0);
  for (int kt = 0; kt < cnt; ++kt) {
    __syncthreads();
    if (kt + 1 < cnt) stage(kt0 + kt + 1, (kt + 1) & 1);
    const __bf16* ks_ = Ks[kt & 1];
    const __bf16* vs_ = Vs[kt & 1];

    bf16x8 kb0[4], kb1[4], vb0[4], vb1[4];
#pragma unroll
    for (int fn = 0; fn < 4; ++fn) {
      const int rb = (fn * 16 + lq) * 64;
      kb0[fn] = *(const bf16x8*)&ks_[rb + sw0];
      kb1[fn] = *(const bf16x8*)&ks_[rb + sw1];
      vb0[fn] = *(const bf16x8*)&vs_[rb + sw0];
      vb1[fn] = *(const bf16x8*)&vs_[rb + sw1];
    }
    f32x4 s[2][4];
#pragma unroll
    for (int fm = 0; fm < 2; ++fm)
#pragma unroll
      for (int fn = 0; fn < 4; ++fn) {
        f32x4 a = __builtin_amdgcn_mfma_f32_16x16x32_bf16(aq[fm][0], kb0[fn], minit, 0, 0, 0);
        s[fm][fn] = __builtin_amdgcn_mfma_f32_16x16x32_bf16(aq[fm][1], kb1[fn], a, 0, 0, 0);
      }

#pragma unroll
    for (int fm = 0; fm < 2; ++fm)
#pragma unroll
      for (int r = 0; r < 4; ++r) {
        const float p0 = __builtin_amdgcn_exp2f(s[fm][0][r]);
        const float p1 = __builtin_amdgcn_exp2f(s[fm][1][r]);
        const float p2 = __builtin_amdgcn_exp2f(s[fm][2][r]);
        const float p3 = __builtin_amdgcn_exp2f(s[fm][3][r]);
        lr[fm][r] += (p0 + p1) + (p2 + p3);
        bf16x4 pk = {(__bf16)p0, (__bf16)p1, (__bf16)p2, (__bf16)p3};
        *(bf16x4*)&myP[(fm * 16 + quad * 4 + r) * 72 + lq * 4] = pk;
      }

#pragma unroll
    for (int fm = 0; fm < 2; ++fm) {
      bf16x8 ap0 = *(const bf16x8*)&myP[(fm * 16 + lq) * 72 + quad * 8];
      bf16x8 ap1 = *(const bf16x8*)&myP[(fm * 16 + lq) * 72 + 32 + quad * 8];
#pragma unroll
      for (int fn = 0; fn < 4; ++fn) {
        o[fm][fn] = __builtin_amdgcn_mfma_f32_16x16x32_bf16(ap0, vb0[fn], o[fm][fn], 0, 0, 0);
        o[fm][fn] = __builtin_amdgcn_mfma_f32_16x16x32_bf16(ap1, vb1[fn], o[fm][fn], 0, 0, 0);
      }
    }
  }

  const int b = bh >> 3, h = bh & 7;
#pragma unroll
  for (int fm = 0; fm < 2; ++fm) {
    const int qrow0 = qt * 128 + w * 32 + fm * 16 + quad * 4;
#pragma unroll
    for (int r = 0; r < 4; ++r) {
      float sum = lr[fm][r];
#pragma unroll
      for (int off = 1; off < 16; off <<= 1) sum += __shfl_xor(sum, off, 64);
      if (lq == 0) pl[(size_t)kh * 32768 + bh * kN + qrow0 + r] = sum;
      const size_t ob = ((size_t)kh * kTok + b * kN + qrow0 + r) * kDim + h * 64;
#pragma unroll
      for (int fn = 0; fn < 4; ++fn) po[ob + fn * 16 + lq] = (__bf16)o[fm][fn][r];
    }
  }
}

// ===== out-proj GEMM with fused split-K combine (T14-pipelined) ============
// C[M,512] = ((sum_kh po_kh) / (sum_kh l_kh)) * B^T. A is reg-staged with
// issue-early/write-late: global loads for tile i+1 issue right after the
// barrier (with B's gld16), the MFMA cluster hides their latency, then
// vmcnt-wait + f32 combine + swizzled ds_write land before the next barrier.
// Combine math is bit-identical to the old combine->ao->gemm64 path.
__global__ __launch_bounds__(256, 2) void gemm64c(const __bf16* __restrict__ po,
                                                  const float* __restrict__ pl,
                                                  const __bf16* __restrict__ B,
                                                  float* __restrict__ C) {
  const int N = kDim, K = kDim;
  const int tid = threadIdx.x;
  const int w = tid >> 6, lane = tid & 63, quad = lane >> 4, lq = lane & 15;
  const int m0 = blockIdx.y * 64;
  const int n0 = blockIdx.x * 64;
  const int wm = (w >> 1) * 32, wn = (w & 1) * 32;
  __shared__ __bf16 As[2][4096];
  __shared__ __bf16 Bs[2][4096];

  const f32x4 zero = {0.f, 0.f, 0.f, 0.f};
  f32x4 acc00 = zero, acc01 = zero, acc10 = zero, acc11 = zero;

  const int sr = tid >> 3, ch = tid & 7;
  bf16x8 pA[2][3];
  float plv[2][3];
  auto issueA = [&](int k0) {
    const int h = k0 >> 6;  // A-col group == head
#pragma unroll
    for (int j = 0; j < 2; ++j) {
      const int m = m0 + j * 32 + sr;
      const int b = m >> 11, qrow = m & (kN - 1);
      const int idx = ((b * kH + h) << 11) + qrow;
      plv[j][0] = pl[idx];
      plv[j][1] = pl[32768 + idx];
      plv[j][2] = pl[65536 + idx];
      const size_t off = (size_t)m * K + k0 + ch * 8;
#pragma unroll
      for (int p = 0; p < 3; ++p)
        pA[j][p] = *(const bf16x8*)(po + (size_t)p * kTok * kDim + off);
    }
  };
  auto writeA = [&](int buf) {
#pragma unroll
    for (int j = 0; j < 2; ++j) {
      const int row = j * 32 + sr;
      const float inv = 1.f / ((plv[j][0] + plv[j][1]) + plv[j][2]);
      bf16x8 t;
#pragma unroll
      for (int e = 0; e < 8; ++e)
        t[e] = (__bf16)((((float)pA[j][0][e] + (float)pA[j][1][e]) + (float)pA[j][2][e]) * inv);
      *(bf16x8*)&As[buf][row * 64 + ((ch ^ (row & 7)) << 3)] = t;
    }
  };
  auto stageB = [&](int k0, int buf) {
#pragma unroll
    for (int j = 0; j < 2; ++j) {
      const int row = j * 32 + sr;
      const int src = k0 + ((ch ^ (row & 7)) << 3);
      gld16(B + (size_t)(n0 + row) * K + src, &Bs[buf][row * 64 + ch * 8]);
    }
  };
  const int sw0 = ((quad ^ (lq & 7)) << 3);
  const int sw1 = (((4 | quad) ^ (lq & 7)) << 3);

  issueA(0);
  writeA(0);
  stageB(0, 0);
  for (int i = 0; i < 8; ++i) {
    __syncthreads();
    if (i + 1 < 8) {
      issueA((i + 1) << 6);          // global->reg, latency hidden by MFMAs
      stageB((i + 1) << 6, (i + 1) & 1);
    }
    const __bf16* as = As[i & 1];
    const __bf16* bs = Bs[i & 1];
#pragma unroll
    for (int ks = 0; ks < 2; ++ks) {
      const int sw = ks ? sw1 : sw0;
      bf16x8 a0 = *(const bf16x8*)&as[(wm +      lq) * 64 + sw];
      bf16x8 a1 = *(const bf16x8*)&as[(wm + 16 + lq) * 64 + sw];
      bf16x8 b0 = *(const bf16x8*)&bs[(wn +      lq) * 64 + sw];
      bf16x8 b1 = *(const bf16x8*)&bs[(wn + 16 + lq) * 64 + sw];
      acc00 = __builtin_amdgcn_mfma_f32_16x16x32_bf16(a0, b0, acc00, 0, 0, 0);
      acc01 = __builtin_amdgcn_mfma_f32_16x16x32_bf16(a0, b1, acc01, 0, 0, 0);
      acc10 = __builtin_amdgcn_mfma_f32_16x16x32_bf16(a1, b0, acc10, 0, 0, 0);
      acc11 = __builtin_amdgcn_mfma_f32_16x16x32_bf16(a1, b1, acc11, 0, 0, 0);
    }
    if (i + 1 < 8) writeA((i + 1) & 1);  // after MFMAs: loads have landed
  }
  const f32x4 av[2][2] = {{acc00, acc01}, {acc10, acc11}};
#pragma unroll
  for (int fm = 0; fm < 2; ++fm)
#pragma unroll
    for (int fn = 0; fn < 2; ++fn)
#pragma unroll
      for (int r = 0; r < 4; ++r)
        C[(size_t)(m0 + wm + fm * 16 + quad * 4 + r) * N + (n0 + wn + fn * 16 + lq)] =
            av[fm][fn][r];
}

// ===========================================================================
extern "C" void kernel_launch(void* const* d_in, const int* in_sizes, int n_in,
                              void* d_out, int out_size, void* d_ws, size_t ws_size,
                              hipStream_t stream) {
  const float* x    = (const float*)d_in[0];
  const float* Wq   = (const float*)d_in[1];
  const float* Wkv  = (const float*)d_in[2];
  const float* Wout = (const float*)d_in[3];
  float* out = (float*)d_out;
  char* ws = (char*)d_ws;

  __bf16* xb    = (__bf16*)(ws);                       //  0..4M   [4096,512]
  __bf16* wqkvb = (__bf16*)(ws + (size_t)(4 << 20));   //  4..5.5M [1536,512]
  __bf16* wob   = (__bf16*)(ws + (size_t)(6 << 20));   //  6..6.5M [512,512]
  __bf16* qn    = (__bf16*)(ws + (size_t)(7 << 20));   //  7..11M  [bh][n][d]
  __bf16* kn    = (__bf16*)(ws + (size_t)(11 << 20));  // 11..15M  [bh][n][d]
  __bf16* vt2   = (__bf16*)(ws + (size_t)(15 << 20));  // 15..19M  tiled V^T
  __bf16* po    = (__bf16*)(ws + (size_t)(19 << 20));  // 19..31M  partials x3
  float*  pl    = (float*)(ws + (size_t)(32 << 20));   // 32..32.4M

  cvt_all<<<1536, 256, 0, stream>>>(x, Wq, Wkv, Wout, xb, wqkvb, wob);
  gemm_qkv<<<dim3(kNQKV / 64, kTok / 128), 256, 0, stream>>>(xb, wqkvb, qn, kn, vt2);
  attn<<<dim3(kN / 128, kB * kH, kKH), 256, 0, stream>>>(qn, kn, vt2, po, pl);
  gemm64c<<<dim3(kDim / 64, kTok / 64), 256, 0, stream>>>(po, pl, wob, out);
}

// Round 8
// 115.927 us; speedup vs baseline: 1.0807x; 1.0807x over previous
//
#include <hip/hip_runtime.h>

typedef __bf16 bf16x8 __attribute__((ext_vector_type(8)));
typedef __bf16 bf16x4 __attribute__((ext_vector_type(4)));
typedef __bf16 bf16x2 __attribute__((ext_vector_type(2)));
typedef float  f32x4  __attribute__((ext_vector_type(4)));
typedef unsigned int u32x2 __attribute__((ext_vector_type(2)));
typedef unsigned int u32x4 __attribute__((ext_vector_type(4)));

#define LOG2E_F 1.44269504088896340736f

static constexpr int kB = 2, kN = 2048, kH = 8, kD = 64, kDim = 512;
static constexpr int kTok = kB * kN;   // 4096
static constexpr int kNQKV = 1536;     // fused Wq(512)+Wkv(1024) rows
static constexpr int kKH = 3;          // attention split-K: 11/11/10 kt tiles

__device__ __forceinline__ void gld16(const void* g, void* l) {
  __builtin_amdgcn_global_load_lds(
      (const __attribute__((address_space(1))) void*)g,
      (__attribute__((address_space(3))) void*)l, 16, 0, 0);
}

__device__ __forceinline__ unsigned pkbf(float a, float b) {
  bf16x2 v; v[0] = (__bf16)a; v[1] = (__bf16)b;
  return __builtin_bit_cast(unsigned, v);
}

// XOR-swizzled LDS tiles (rows of 64 bf16 = 8 chunks of 16B):
// LDS chunk c of row r holds GLOBAL chunk c^(r&7). Staged via per-lane source
// permutation (gld16 dest stays lane-linear); readers XOR their chunk index
// with (row&7). Spreads quad-group b128 reads over all 32 banks.

// ===== fp32 -> bf16 linear converts: x | Wq | Wkv (fused) | Wout ===========
__global__ __launch_bounds__(256) void cvt_all(const float* __restrict__ x,
                                               const float* __restrict__ wq,
                                               const float* __restrict__ wkv,
                                               const float* __restrict__ wo,
                                               __bf16* __restrict__ xb,
                                               __bf16* __restrict__ wqkvb,
                                               __bf16* __restrict__ wob) {
  size_t i = ((size_t)blockIdx.x * 256 + threadIdx.x) * 8;
  const float* s; __bf16* d; size_t off;
  if (i < 2097152)      { s = x;   d = xb;              off = i; }
  else if (i < 2359296) { s = wq;  d = wqkvb;           off = i - 2097152; }
  else if (i < 2883584) { s = wkv; d = wqkvb + 262144;  off = i - 2359296; }
  else                  { s = wo;  d = wob;             off = i - 2883584; }
  float4 u = *(const float4*)(s + off);
  float4 v = *(const float4*)(s + off + 4);
  bf16x8 t;
  t[0] = (__bf16)u.x; t[1] = (__bf16)u.y; t[2] = (__bf16)u.z; t[3] = (__bf16)u.w;
  t[4] = (__bf16)v.x; t[5] = (__bf16)v.y; t[6] = (__bf16)v.z; t[7] = (__bf16)v.w;
  *(bf16x8*)(d + off) = t;
}

// ===== QKV GEMM with fused norm/transpose epilogue =========================
__global__ __launch_bounds__(256, 3) void gemm_qkv(const __bf16* __restrict__ A,
                                                   const __bf16* __restrict__ B,
                                                   __bf16* __restrict__ qn,
                                                   __bf16* __restrict__ kn,
                                                   __bf16* __restrict__ vt2) {
  const int K = kDim;
  const int tid = threadIdx.x;
  const int w = tid >> 6, lane = tid & 63, quad = lane >> 4, lq = lane & 15;
  const int m0 = blockIdx.y * 128;
  const int n0 = blockIdx.x * 64;
  const int wm = w * 32;
  __shared__ __bf16 As[2][128 * 64];
  __shared__ __bf16 Bs[2][64 * 64];

  const f32x4 zero = {0.f, 0.f, 0.f, 0.f};
  f32x4 acc[2][4];
#pragma unroll
  for (int fm = 0; fm < 2; ++fm)
#pragma unroll
    for (int fn = 0; fn < 4; ++fn) acc[fm][fn] = zero;

  const int sr = tid >> 3, ch = tid & 7;
  auto stage = [&](int k0, int buf) {
#pragma unroll
    for (int j = 0; j < 4; ++j) {
      const int row = j * 32 + sr;
      gld16(A + (size_t)(m0 + row) * K + k0 + ((ch ^ (row & 7)) << 3),
            &As[buf][row * 64 + ch * 8]);
    }
#pragma unroll
    for (int j = 0; j < 2; ++j) {
      const int row = j * 32 + sr;
      gld16(B + (size_t)(n0 + row) * K + k0 + ((ch ^ (row & 7)) << 3),
            &Bs[buf][row * 64 + ch * 8]);
    }
  };
  const int sw0 = ((quad ^ (lq & 7)) << 3);        // ks=0
  const int sw1 = (((4 | quad) ^ (lq & 7)) << 3);  // ks=1

  stage(0, 0);
  for (int i = 0; i < 8; ++i) {
    __syncthreads();
    if (i + 1 < 8) stage((i + 1) << 6, (i + 1) & 1);
    const __bf16* as = As[i & 1];
    const __bf16* bs = Bs[i & 1];
#pragma unroll
    for (int ks = 0; ks < 2; ++ks) {
      const int sw = ks ? sw1 : sw0;
      bf16x8 a[2], b[4];
#pragma unroll
      for (int fm = 0; fm < 2; ++fm)
        a[fm] = *(const bf16x8*)&as[(wm + fm * 16 + lq) * 64 + sw];
#pragma unroll
      for (int fn = 0; fn < 4; ++fn)
        b[fn] = *(const bf16x8*)&bs[(fn * 16 + lq) * 64 + sw];
#pragma unroll
      for (int fm = 0; fm < 2; ++fm)
#pragma unroll
        for (int fn = 0; fn < 4; ++fn)
          acc[fm][fn] =
              __builtin_amdgcn_mfma_f32_16x16x32_bf16(a[fm], b[fn], acc[fm][fn], 0, 0, 0);
    }
  }

  const int h = (n0 >> 6) & 7;
  if (n0 >= 1024) {
    // ---- V: transpose via LDS (reuse As), then coalesced 16B stores ----
    __syncthreads();
    __bf16* Ts = &As[0][0];  // [2 tiles][64 d][stride 72]
#pragma unroll
    for (int fm = 0; fm < 2; ++fm)
#pragma unroll
      for (int r = 0; r < 4; ++r) {
        const int mo = wm + fm * 16 + quad * 4 + r;
        const int tau = mo >> 6, tt = mo & 63;
        const int p = (tt & 15) * 4 + (tt >> 4);  // inverse of attn's pi
#pragma unroll
        for (int fn = 0; fn < 4; ++fn)
          Ts[tau * 4608 + (fn * 16 + lq) * 72 + p] = (__bf16)acc[fm][fn][r];
      }
    __syncthreads();
    const int b = m0 >> 11, kt0 = (m0 & (kN - 1)) >> 6;
    const int dd = tid >> 2, p0 = (tid & 3) << 4;
#pragma unroll
    for (int tau = 0; tau < 2; ++tau) {
      const __bf16* src = Ts + tau * 4608 + dd * 72 + p0;
      __bf16* dst = vt2 + ((size_t)((b * kH + h) * 32 + kt0 + tau)) * 4096 + tid * 16;
      *(bf16x8*)dst = *(const bf16x8*)src;
      *(bf16x8*)(dst + 8) = *(const bf16x8*)(src + 8);
    }
  } else {
    // ---- Q/K: rms over the 64 cols ----
    const float qs = (n0 < 512) ? (0.125f * LOG2E_F) : 1.0f;
    __bf16* dst0 = (n0 < 512) ? qn : kn;
#pragma unroll
    for (int fm = 0; fm < 2; ++fm)
#pragma unroll
      for (int r = 0; r < 4; ++r) {
        float ss = 0.f;
#pragma unroll
        for (int fn = 0; fn < 4; ++fn) ss += acc[fm][fn][r] * acc[fm][fn][r];
#pragma unroll
        for (int off = 1; off < 16; off <<= 1) ss += __shfl_xor(ss, off, 64);
        const float inv = qs / (sqrtf(ss * (1.f / 64)) + 1e-4f);
        const int m = m0 + wm + fm * 16 + quad * 4 + r;
        const int b = m >> 11, n = m & (kN - 1);
        __bf16* dst = dst0 + ((size_t)(b * kH + h) * kN + n) * kD;
#pragma unroll
        for (int fn = 0; fn < 4; ++fn)
          dst[fn * 16 + lq] = (__bf16)(acc[fm][fn][r] * inv);
      }
  }
}

// ===== fused attention: block = (128-q tile, bh, key-third) ================
// Round-0 baseline structure (split-K3 11/11/10, 3 blocks/CU), with ONE
// delta: softmax IN-REGISTER via swapped QK^T (S^T = mfma(K,Q)) -- the
// permlane redistribution verified correct in round 6. Lane holds
// P[q=lq][key = fn*16+quad*4+r]; PV A-frag wants element e of pa[ks] = key
// at V-column c = ks*32+quad*8+e, i.e. key t = (c&3)*16 + (c>>2): adjacent
// elements are keys 16 apart (different fn). Pack fn-PAIRS at equal r:
//   Wp[j][r] = pkbf(p[2j][r], p[2j+1][r])           (keys t, t+16)
// word wi of pa[ks] at dest (quad,lq) = Wp[wi&1][2*(quad&1)+(wi>>1)] from
// source quad 2ks+(quad>>1), realized by (u,v)=permlane16_swap(a,c) then
// (w_ks0,w_ks1)=permlane32_swap(u,v). Deletes the Ps LDS round-trip
// (8 ds_write_b64 + 4 ds_read_b128 + lgkm stalls per kt per wave).
// (256,3): VGPR cap ~168 >= ~150 live set (R6's (256,4)=128 cap spilled).
// Fixed-max softmax (|s| <= 11.54 < 12; bias -12 in MFMA C-init).
__global__ __launch_bounds__(256, 3) void attn(const __bf16* __restrict__ qn,
                                               const __bf16* __restrict__ kn,
                                               const __bf16* __restrict__ vt2,
                                               __bf16* __restrict__ po,
                                               float* __restrict__ pl) {
  const int qt = blockIdx.x, bh = blockIdx.y, kh = blockIdx.z;
  const int kt0 = kh * 11;
  const int cnt = (kh == 2) ? 10 : 11;
  const int tid = threadIdx.x;
  const int w = tid >> 6, lane = tid & 63, quad = lane >> 4, lq = lane & 15;
  __shared__ __bf16 Ks[2][4096];
  __shared__ __bf16 Vs[2][4096];

  bf16x8 aq[2][2];
#pragma unroll
  for (int fm = 0; fm < 2; ++fm) {
    const __bf16* Qb = qn + ((size_t)bh * kN + qt * 128 + w * 32 + fm * 16 + lq) * kD;
    aq[fm][0] = *(const bf16x8*)(Qb + quad * 8);
    aq[fm][1] = *(const bf16x8*)(Qb + 32 + quad * 8);
  }

  const f32x4 zero  = {0.f, 0.f, 0.f, 0.f};
  const f32x4 minit = {-12.f, -12.f, -12.f, -12.f};
  f32x4 o[2][4];
  float lr[2] = {0.f, 0.f};
#pragma unroll
  for (int fm = 0; fm < 2; ++fm)
#pragma unroll
    for (int i = 0; i < 4; ++i) o[fm][i] = zero;

  const __bf16* Kb = kn + (size_t)bh * kN * kD;   // tile ktg at +ktg*4096
  const __bf16* Vb = vt2 + (size_t)bh * 32 * 4096;

  auto stage = [&](int ktg, int buf) {
#pragma unroll
    for (int j = 0; j < 2; ++j) {
      const int s = j * 256 + tid;
      const int row = s >> 3, ch = s & 7;
      const int src = row * 64 + ((ch ^ (row & 7)) << 3);
      gld16(Kb + (size_t)ktg * 4096 + src, &Ks[buf][s * 8]);
      gld16(Vb + (size_t)ktg * 4096 + src, &Vs[buf][s * 8]);
    }
  };
  const int sw0 = ((quad ^ (lq & 7)) << 3);
  const int sw1 = (((4 | quad) ^ (lq & 7)) << 3);

  stage(kt0, 0);
  for (int kt = 0; kt < cnt; ++kt) {
    __syncthreads();
    if (kt + 1 < cnt) stage(kt0 + kt + 1, (kt + 1) & 1);
    const __bf16* ks_ = Ks[kt & 1];
    const __bf16* vs_ = Vs[kt & 1];

    bf16x8 kb0[4], kb1[4];
#pragma unroll
    for (int fn = 0; fn < 4; ++fn) {
      const int rb = (fn * 16 + lq) * 64;
      kb0[fn] = *(const bf16x8*)&ks_[rb + sw0];
      kb1[fn] = *(const bf16x8*)&ks_[rb + sw1];
    }

    bf16x8 pa[2][2];
#pragma unroll
    for (int fm = 0; fm < 2; ++fm) {
      // S^T = K·Q^T (+ -12 bias): lane -> q=lq, key=fn*16+quad*4+r
      f32x4 s[4];
#pragma unroll
      for (int fn = 0; fn < 4; ++fn) {
        f32x4 a = __builtin_amdgcn_mfma_f32_16x16x32_bf16(kb0[fn], aq[fm][0], minit, 0, 0, 0);
        s[fn] = __builtin_amdgcn_mfma_f32_16x16x32_bf16(kb1[fn], aq[fm][1], a, 0, 0, 0);
      }
      float p[4][4];
      float ls = 0.f;
#pragma unroll
      for (int fn = 0; fn < 4; ++fn)
#pragma unroll
        for (int r = 0; r < 4; ++r) {
          p[fn][r] = __builtin_amdgcn_exp2f(s[fn][r]);
          ls += p[fn][r];
        }
      lr[fm] += ls;
      unsigned Wp[2][4];
#pragma unroll
      for (int j = 0; j < 2; ++j)
#pragma unroll
        for (int r = 0; r < 4; ++r) Wp[j][r] = pkbf(p[2 * j][r], p[2 * j + 1][r]);
      unsigned pw[2][4];
#pragma unroll
      for (int wi = 0; wi < 4; ++wi) {
        const int j = wi & 1, dl = wi >> 1;
        u32x2 t1 = __builtin_amdgcn_permlane16_swap(Wp[j][dl], Wp[j][2 + dl], false, false);
        u32x2 t2 = __builtin_amdgcn_permlane32_swap(t1[0], t1[1], false, false);
        pw[0][wi] = t2[0]; pw[1][wi] = t2[1];
      }
#pragma unroll
      for (int ks = 0; ks < 2; ++ks) {
        u32x4 pv = {pw[ks][0], pw[ks][1], pw[ks][2], pw[ks][3]};
        pa[fm][ks] = __builtin_bit_cast(bf16x8, pv);
      }
    }

    bf16x8 vb0[4], vb1[4];
#pragma unroll
    for (int fn = 0; fn < 4; ++fn) {
      const int rb = (fn * 16 + lq) * 64;
      vb0[fn] = *(const bf16x8*)&vs_[rb + sw0];
      vb1[fn] = *(const bf16x8*)&vs_[rb + sw1];
    }
#pragma unroll
    for (int fm = 0; fm < 2; ++fm)
#pragma unroll
      for (int fn = 0; fn < 4; ++fn) {
        o[fm][fn] = __builtin_amdgcn_mfma_f32_16x16x32_bf16(pa[fm][0], vb0[fn], o[fm][fn], 0, 0, 0);
        o[fm][fn] = __builtin_amdgcn_mfma_f32_16x16x32_bf16(pa[fm][1], vb1[fn], o[fm][fn], 0, 0, 0);
      }
  }

  const int b = bh >> 3, h = bh & 7;
#pragma unroll
  for (int fm = 0; fm < 2; ++fm) {
    // lane holds partial denom for q = fm*16+lq over its 16 keys -> sum quads
    float sum = lr[fm];
    sum += __shfl_xor(sum, 16, 64);
    sum += __shfl_xor(sum, 32, 64);
    const int qbase = qt * 128 + w * 32 + fm * 16;
    if (quad == 0) pl[(size_t)kh * 32768 + bh * kN + qbase + lq] = sum;
#pragma unroll
    for (int r = 0; r < 4; ++r) {
      const size_t ob = ((size_t)kh * kTok + b * kN + qbase + quad * 4 + r) * kDim + h * 64;
#pragma unroll
      for (int fn = 0; fn < 4; ++fn) po[ob + fn * 16 + lq] = (__bf16)o[fm][fn][r];
    }
  }
}

// ===== combine thirds: ao = (sum o_kh)/(sum l_kh), bf16 ====================
__global__ __launch_bounds__(256) void combine(const __bf16* __restrict__ po,
                                               const float* __restrict__ pl,
                                               __bf16* __restrict__ ao) {
  const size_t i = ((size_t)blockIdx.x * 256 + threadIdx.x) * 4;
  const int tok = (int)(i >> 9), dk = (int)(i & 511);
  const int h = dk >> 6, b = tok >> 11, qrow = tok & (kN - 1);
  const int idx = (b * kH + h) * kN + qrow;
  float l = 0.f;
#pragma unroll
  for (int kh = 0; kh < kKH; ++kh) l += pl[kh * 32768 + idx];
  const float inv = 1.f / l;
  float s0 = 0.f, s1 = 0.f, s2 = 0.f, s3 = 0.f;
#pragma unroll
  for (int kh = 0; kh < kKH; ++kh) {
    bf16x4 a = *(const bf16x4*)(po + (size_t)kh * kTok * kDim + i);
    s0 += (float)a[0]; s1 += (float)a[1]; s2 += (float)a[2]; s3 += (float)a[3];
  }
  bf16x4 t = {(__bf16)(s0 * inv), (__bf16)(s1 * inv),
              (__bf16)(s2 * inv), (__bf16)(s3 * inv)};
  *(bf16x4*)(ao + i) = t;
}

// ===== out-proj GEMM: C[M,512] = A*B^T, 64x64 tile =========================
__global__ __launch_bounds__(256, 2) void gemm64(const __bf16* __restrict__ A,
                                                 const __bf16* __restrict__ B,
                                                 float* __restrict__ C,
                                                 int N, int K) {
  const int tid = threadIdx.x;
  const int w = tid >> 6, lane = tid & 63, quad = lane >> 4, lq = lane & 15;
  const int m0 = blockIdx.y * 64;
  const int n0 = blockIdx.x * 64;
  const int wm = (w >> 1) * 32, wn = (w & 1) * 32;
  __shared__ __bf16 As[2][4096];
  __shared__ __bf16 Bs[2][4096];

  const f32x4 zero = {0.f, 0.f, 0.f, 0.f};
  f32x4 acc00 = zero, acc01 = zero, acc10 = zero, acc11 = zero;

  const int sr = tid >> 3, ch = tid & 7;
  auto stage = [&](int k0, int buf) {
#pragma unroll
    for (int j = 0; j < 2; ++j) {
      const int row = j * 32 + sr;
      const int src = k0 + ((ch ^ (row & 7)) << 3);
      gld16(A + (size_t)(m0 + row) * K + src, &As[buf][row * 64 + ch * 8]);
      gld16(B + (size_t)(n0 + row) * K + src, &Bs[buf][row * 64 + ch * 8]);
    }
  };
  const int sw0 = ((quad ^ (lq & 7)) << 3);
  const int sw1 = (((4 | quad) ^ (lq & 7)) << 3);

  stage(0, 0);
  const int iters = K >> 6;
  for (int i = 0; i < iters; ++i) {
    __syncthreads();
    if (i + 1 < iters) stage((i + 1) << 6, (i + 1) & 1);
    const __bf16* as = As[i & 1];
    const __bf16* bs = Bs[i & 1];
#pragma unroll
    for (int ks = 0; ks < 2; ++ks) {
      const int sw = ks ? sw1 : sw0;
      bf16x8 a0 = *(const bf16x8*)&as[(wm +      lq) * 64 + sw];
      bf16x8 a1 = *(const bf16x8*)&as[(wm + 16 + lq) * 64 + sw];
      bf16x8 b0 = *(const bf16x8*)&bs[(wn +      lq) * 64 + sw];
      bf16x8 b1 = *(const bf16x8*)&bs[(wn + 16 + lq) * 64 + sw];
      acc00 = __builtin_amdgcn_mfma_f32_16x16x32_bf16(a0, b0, acc00, 0, 0, 0);
      acc01 = __builtin_amdgcn_mfma_f32_16x16x32_bf16(a0, b1, acc01, 0, 0, 0);
      acc10 = __builtin_amdgcn_mfma_f32_16x16x32_bf16(a1, b0, acc10, 0, 0, 0);
      acc11 = __builtin_amdgcn_mfma_f32_16x16x32_bf16(a1, b1, acc11, 0, 0, 0);
    }
  }
  const f32x4 av[2][2] = {{acc00, acc01}, {acc10, acc11}};
#pragma unroll
  for (int fm = 0; fm < 2; ++fm)
#pragma unroll
    for (int fn = 0; fn < 2; ++fn)
#pragma unroll
      for (int r = 0; r < 4; ++r)
        C[(size_t)(m0 + wm + fm * 16 + quad * 4 + r) * N + (n0 + wn + fn * 16 + lq)] =
            av[fm][fn][r];
}

// ===========================================================================
extern "C" void kernel_launch(void* const* d_in, const int* in_sizes, int n_in,
                              void* d_out, int out_size, void* d_ws, size_t ws_size,
                              hipStream_t stream) {
  const float* x    = (const float*)d_in[0];
  const float* Wq   = (const float*)d_in[1];
  const float* Wkv  = (const float*)d_in[2];
  const float* Wout = (const float*)d_in[3];
  float* out = (float*)d_out;
  char* ws = (char*)d_ws;

  __bf16* xb    = (__bf16*)(ws);                       //  0..4M   [4096,512]
  __bf16* wqkvb = (__bf16*)(ws + (size_t)(4 << 20));   //  4..5.5M [1536,512]
  __bf16* wob   = (__bf16*)(ws + (size_t)(6 << 20));   //  6..6.5M [512,512]
  __bf16* qn    = (__bf16*)(ws + (size_t)(7 << 20));   //  7..11M  [bh][n][d]
  __bf16* kn    = (__bf16*)(ws + (size_t)(11 << 20));  // 11..15M  [bh][n][d]
  __bf16* vt2   = (__bf16*)(ws + (size_t)(15 << 20));  // 15..19M  tiled V^T
  __bf16* po    = (__bf16*)(ws + (size_t)(19 << 20));  // 19..31M  partials x3
  float*  pl    = (float*)(ws + (size_t)(32 << 20));   // 32..32.4M
  __bf16* ao    = (__bf16*)(ws + (size_t)(33 << 20));  // 33..37M  [tok][dim]

  cvt_all<<<1536, 256, 0, stream>>>(x, Wq, Wkv, Wout, xb, wqkvb, wob);
  gemm_qkv<<<dim3(kNQKV / 64, kTok / 128), 256, 0, stream>>>(xb, wqkvb, qn, kn, vt2);
  attn<<<dim3(kN / 128, kB * kH, kKH), 256, 0, stream>>>(qn, kn, vt2, po, pl);
  combine<<<kTok * kDim / 1024, 256, 0, stream>>>(po, pl, ao);
  gemm64<<<dim3(kDim / 64, kTok / 64), 256, 0, stream>>>(ao, wob, out, kDim, kDim);
}

// Round 9
// 115.182 us; speedup vs baseline: 1.0877x; 1.0065x over previous
//
#include <hip/hip_runtime.h>

typedef __bf16 bf16x8 __attribute__((ext_vector_type(8)));
typedef __bf16 bf16x4 __attribute__((ext_vector_type(4)));
typedef __bf16 bf16x2 __attribute__((ext_vector_type(2)));
typedef float  f32x4  __attribute__((ext_vector_type(4)));
typedef unsigned int u32x2 __attribute__((ext_vector_type(2)));
typedef unsigned int u32x4 __attribute__((ext_vector_type(4)));

#define LOG2E_F 1.44269504088896340736f

static constexpr int kB = 2, kN = 2048, kH = 8, kD = 64, kDim = 512;
static constexpr int kTok = kB * kN;   // 4096
static constexpr int kNQKV = 1536;     // fused Wq(512)+Wkv(1024) rows
static constexpr int kKH = 3;          // attention split-K: 11/11/10 kt tiles

__device__ __forceinline__ void gld16(const void* g, void* l) {
  __builtin_amdgcn_global_load_lds(
      (const __attribute__((address_space(1))) void*)g,
      (__attribute__((address_space(3))) void*)l, 16, 0, 0);
}

__device__ __forceinline__ unsigned pkbf(float a, float b) {
  bf16x2 v; v[0] = (__bf16)a; v[1] = (__bf16)b;
  return __builtin_bit_cast(unsigned, v);
}

// XOR-swizzled LDS tiles (rows of 64 bf16 = 8 chunks of 16B):
// LDS chunk c of row r holds GLOBAL chunk c^(r&7). Staged via per-lane source
// permutation (gld16 dest stays lane-linear); readers XOR their chunk index
// with (row&7). Spreads quad-group b128 reads over all 32 banks.
//
// T1 XCD remap (this round): attn and gemm_qkv launch 1-D (768 = 96 x 8,
// bijective swz = (bid&7)*96 + bid/8) decoded so each XCD owns contiguous
// work sharing operand panels: attn -> 6 full (bh,kh) K/V sets (528 KB) per
// XCD; gemm_qkv -> 4 A-panels + B per XCD. Pure index remap, no numerics.

// ===== fp32 -> bf16 linear converts: x | Wq | Wkv (fused) | Wout ===========
__global__ __launch_bounds__(256) void cvt_all(const float* __restrict__ x,
                                               const float* __restrict__ wq,
                                               const float* __restrict__ wkv,
                                               const float* __restrict__ wo,
                                               __bf16* __restrict__ xb,
                                               __bf16* __restrict__ wqkvb,
                                               __bf16* __restrict__ wob) {
  size_t i = ((size_t)blockIdx.x * 256 + threadIdx.x) * 8;
  const float* s; __bf16* d; size_t off;
  if (i < 2097152)      { s = x;   d = xb;              off = i; }
  else if (i < 2359296) { s = wq;  d = wqkvb;           off = i - 2097152; }
  else if (i < 2883584) { s = wkv; d = wqkvb + 262144;  off = i - 2359296; }
  else                  { s = wo;  d = wob;             off = i - 2883584; }
  float4 u = *(const float4*)(s + off);
  float4 v = *(const float4*)(s + off + 4);
  bf16x8 t;
  t[0] = (__bf16)u.x; t[1] = (__bf16)u.y; t[2] = (__bf16)u.z; t[3] = (__bf16)u.w;
  t[4] = (__bf16)v.x; t[5] = (__bf16)v.y; t[6] = (__bf16)v.z; t[7] = (__bf16)v.w;
  *(bf16x8*)(d + off) = t;
}

// ===== QKV GEMM with fused norm/transpose epilogue =========================
__global__ __launch_bounds__(256, 3) void gemm_qkv(const __bf16* __restrict__ A,
                                                   const __bf16* __restrict__ B,
                                                   __bf16* __restrict__ qn,
                                                   __bf16* __restrict__ kn,
                                                   __bf16* __restrict__ vt2) {
  const int K = kDim;
  const int tid = threadIdx.x;
  const int w = tid >> 6, lane = tid & 63, quad = lane >> 4, lq = lane & 15;
  // T1: XCD k owns swz in [96k, 96k+96) = 4 m-panels x all 24 n-tiles
  const int bid = blockIdx.x;
  const int swz = (bid & 7) * 96 + (bid >> 3);
  const int m0 = (swz / 24) * 128;
  const int n0 = (swz % 24) * 64;
  const int wm = w * 32;
  __shared__ __bf16 As[2][128 * 64];
  __shared__ __bf16 Bs[2][64 * 64];

  const f32x4 zero = {0.f, 0.f, 0.f, 0.f};
  f32x4 acc[2][4];
#pragma unroll
  for (int fm = 0; fm < 2; ++fm)
#pragma unroll
    for (int fn = 0; fn < 4; ++fn) acc[fm][fn] = zero;

  const int sr = tid >> 3, ch = tid & 7;
  auto stage = [&](int k0, int buf) {
#pragma unroll
    for (int j = 0; j < 4; ++j) {
      const int row = j * 32 + sr;
      gld16(A + (size_t)(m0 + row) * K + k0 + ((ch ^ (row & 7)) << 3),
            &As[buf][row * 64 + ch * 8]);
    }
#pragma unroll
    for (int j = 0; j < 2; ++j) {
      const int row = j * 32 + sr;
      gld16(B + (size_t)(n0 + row) * K + k0 + ((ch ^ (row & 7)) << 3),
            &Bs[buf][row * 64 + ch * 8]);
    }
  };
  const int sw0 = ((quad ^ (lq & 7)) << 3);        // ks=0
  const int sw1 = (((4 | quad) ^ (lq & 7)) << 3);  // ks=1

  stage(0, 0);
  for (int i = 0; i < 8; ++i) {
    __syncthreads();
    if (i + 1 < 8) stage((i + 1) << 6, (i + 1) & 1);
    const __bf16* as = As[i & 1];
    const __bf16* bs = Bs[i & 1];
#pragma unroll
    for (int ks = 0; ks < 2; ++ks) {
      const int sw = ks ? sw1 : sw0;
      bf16x8 a[2], b[4];
#pragma unroll
      for (int fm = 0; fm < 2; ++fm)
        a[fm] = *(const bf16x8*)&as[(wm + fm * 16 + lq) * 64 + sw];
#pragma unroll
      for (int fn = 0; fn < 4; ++fn)
        b[fn] = *(const bf16x8*)&bs[(fn * 16 + lq) * 64 + sw];
#pragma unroll
      for (int fm = 0; fm < 2; ++fm)
#pragma unroll
        for (int fn = 0; fn < 4; ++fn)
          acc[fm][fn] =
              __builtin_amdgcn_mfma_f32_16x16x32_bf16(a[fm], b[fn], acc[fm][fn], 0, 0, 0);
    }
  }

  const int h = (n0 >> 6) & 7;
  if (n0 >= 1024) {
    // ---- V: transpose via LDS (reuse As), then coalesced 16B stores ----
    __syncthreads();
    __bf16* Ts = &As[0][0];  // [2 tiles][64 d][stride 72]
#pragma unroll
    for (int fm = 0; fm < 2; ++fm)
#pragma unroll
      for (int r = 0; r < 4; ++r) {
        const int mo = wm + fm * 16 + quad * 4 + r;
        const int tau = mo >> 6, tt = mo & 63;
        const int p = (tt & 15) * 4 + (tt >> 4);  // inverse of attn's pi
#pragma unroll
        for (int fn = 0; fn < 4; ++fn)
          Ts[tau * 4608 + (fn * 16 + lq) * 72 + p] = (__bf16)acc[fm][fn][r];
      }
    __syncthreads();
    const int b = m0 >> 11, kt0 = (m0 & (kN - 1)) >> 6;
    const int dd = tid >> 2, p0 = (tid & 3) << 4;
#pragma unroll
    for (int tau = 0; tau < 2; ++tau) {
      const __bf16* src = Ts + tau * 4608 + dd * 72 + p0;
      __bf16* dst = vt2 + ((size_t)((b * kH + h) * 32 + kt0 + tau)) * 4096 + tid * 16;
      *(bf16x8*)dst = *(const bf16x8*)src;
      *(bf16x8*)(dst + 8) = *(const bf16x8*)(src + 8);
    }
  } else {
    // ---- Q/K: rms over the 64 cols ----
    const float qs = (n0 < 512) ? (0.125f * LOG2E_F) : 1.0f;
    __bf16* dst0 = (n0 < 512) ? qn : kn;
#pragma unroll
    for (int fm = 0; fm < 2; ++fm)
#pragma unroll
      for (int r = 0; r < 4; ++r) {
        float ss = 0.f;
#pragma unroll
        for (int fn = 0; fn < 4; ++fn) ss += acc[fm][fn][r] * acc[fm][fn][r];
#pragma unroll
        for (int off = 1; off < 16; off <<= 1) ss += __shfl_xor(ss, off, 64);
        const float inv = qs / (sqrtf(ss * (1.f / 64)) + 1e-4f);
        const int m = m0 + wm + fm * 16 + quad * 4 + r;
        const int b = m >> 11, n = m & (kN - 1);
        __bf16* dst = dst0 + ((size_t)(b * kH + h) * kN + n) * kD;
#pragma unroll
        for (int fn = 0; fn < 4; ++fn)
          dst[fn * 16 + lq] = (__bf16)(acc[fm][fn][r] * inv);
      }
  }
}

// ===== fused attention: block = (128-q tile, bh, key-third) ================
// R8 structure (split-K3 11/11/10, in-register permlane softmax, (256,3))
// with ONE delta: T1 XCD remap. 1-D grid 768; swz = (bid&7)*96 + bid/8;
// work index = qt + 16*(bh + 16*kh) -> XCD k owns 6 complete (bh,kh) K/V
// sets (16 qt each), K/V working set 528 KB per XCD L2.
// Softmax IN-REGISTER via swapped QK^T (S^T = mfma(K,Q)); permlane
// redistribution verified R6/R8. Fixed-max softmax (|s| <= 11.54 < 12).
__global__ __launch_bounds__(256, 3) void attn(const __bf16* __restrict__ qn,
                                               const __bf16* __restrict__ kn,
                                               const __bf16* __restrict__ vt2,
                                               __bf16* __restrict__ po,
                                               float* __restrict__ pl) {
  const int bid = blockIdx.x;
  const int swz = (bid & 7) * 96 + (bid >> 3);   // bijective: 768 = 96*8
  const int qt = swz & 15, bhkh = swz >> 4;
  const int bh = bhkh & 15, kh = bhkh >> 4;
  const int kt0 = kh * 11;
  const int cnt = (kh == 2) ? 10 : 11;
  const int tid = threadIdx.x;
  const int w = tid >> 6, lane = tid & 63, quad = lane >> 4, lq = lane & 15;
  __shared__ __bf16 Ks[2][4096];
  __shared__ __bf16 Vs[2][4096];

  bf16x8 aq[2][2];
#pragma unroll
  for (int fm = 0; fm < 2; ++fm) {
    const __bf16* Qb = qn + ((size_t)bh * kN + qt * 128 + w * 32 + fm * 16 + lq) * kD;
    aq[fm][0] = *(const bf16x8*)(Qb + quad * 8);
    aq[fm][1] = *(const bf16x8*)(Qb + 32 + quad * 8);
  }

  const f32x4 zero  = {0.f, 0.f, 0.f, 0.f};
  const f32x4 minit = {-12.f, -12.f, -12.f, -12.f};
  f32x4 o[2][4];
  float lr[2] = {0.f, 0.f};
#pragma unroll
  for (int fm = 0; fm < 2; ++fm)
#pragma unroll
    for (int i = 0; i < 4; ++i) o[fm][i] = zero;

  const __bf16* Kb = kn + (size_t)bh * kN * kD;   // tile ktg at +ktg*4096
  const __bf16* Vb = vt2 + (size_t)bh * 32 * 4096;

  auto stage = [&](int ktg, int buf) {
#pragma unroll
    for (int j = 0; j < 2; ++j) {
      const int s = j * 256 + tid;
      const int row = s >> 3, ch = s & 7;
      const int src = row * 64 + ((ch ^ (row & 7)) << 3);
      gld16(Kb + (size_t)ktg * 4096 + src, &Ks[buf][s * 8]);
      gld16(Vb + (size_t)ktg * 4096 + src, &Vs[buf][s * 8]);
    }
  };
  const int sw0 = ((quad ^ (lq & 7)) << 3);
  const int sw1 = (((4 | quad) ^ (lq & 7)) << 3);

  stage(kt0, 0);
  for (int kt = 0; kt < cnt; ++kt) {
    __syncthreads();
    if (kt + 1 < cnt) stage(kt0 + kt + 1, (kt + 1) & 1);
    const __bf16* ks_ = Ks[kt & 1];
    const __bf16* vs_ = Vs[kt & 1];

    bf16x8 kb0[4], kb1[4];
#pragma unroll
    for (int fn = 0; fn < 4; ++fn) {
      const int rb = (fn * 16 + lq) * 64;
      kb0[fn] = *(const bf16x8*)&ks_[rb + sw0];
      kb1[fn] = *(const bf16x8*)&ks_[rb + sw1];
    }

    bf16x8 pa[2][2];
#pragma unroll
    for (int fm = 0; fm < 2; ++fm) {
      // S^T = K·Q^T (+ -12 bias): lane -> q=lq, key=fn*16+quad*4+r
      f32x4 s[4];
#pragma unroll
      for (int fn = 0; fn < 4; ++fn) {
        f32x4 a = __builtin_amdgcn_mfma_f32_16x16x32_bf16(kb0[fn], aq[fm][0], minit, 0, 0, 0);
        s[fn] = __builtin_amdgcn_mfma_f32_16x16x32_bf16(kb1[fn], aq[fm][1], a, 0, 0, 0);
      }
      float p[4][4];
      float ls = 0.f;
#pragma unroll
      for (int fn = 0; fn < 4; ++fn)
#pragma unroll
        for (int r = 0; r < 4; ++r) {
          p[fn][r] = __builtin_amdgcn_exp2f(s[fn][r]);
          ls += p[fn][r];
        }
      lr[fm] += ls;
      unsigned Wp[2][4];
#pragma unroll
      for (int j = 0; j < 2; ++j)
#pragma unroll
        for (int r = 0; r < 4; ++r) Wp[j][r] = pkbf(p[2 * j][r], p[2 * j + 1][r]);
      unsigned pw[2][4];
#pragma unroll
      for (int wi = 0; wi < 4; ++wi) {
        const int j = wi & 1, dl = wi >> 1;
        u32x2 t1 = __builtin_amdgcn_permlane16_swap(Wp[j][dl], Wp[j][2 + dl], false, false);
        u32x2 t2 = __builtin_amdgcn_permlane32_swap(t1[0], t1[1], false, false);
        pw[0][wi] = t2[0]; pw[1][wi] = t2[1];
      }
#pragma unroll
      for (int ks = 0; ks < 2; ++ks) {
        u32x4 pv = {pw[ks][0], pw[ks][1], pw[ks][2], pw[ks][3]};
        pa[fm][ks] = __builtin_bit_cast(bf16x8, pv);
      }
    }

    bf16x8 vb0[4], vb1[4];
#pragma unroll
    for (int fn = 0; fn < 4; ++fn) {
      const int rb = (fn * 16 + lq) * 64;
      vb0[fn] = *(const bf16x8*)&vs_[rb + sw0];
      vb1[fn] = *(const bf16x8*)&vs_[rb + sw1];
    }
#pragma unroll
    for (int fm = 0; fm < 2; ++fm)
#pragma unroll
      for (int fn = 0; fn < 4; ++fn) {
        o[fm][fn] = __builtin_amdgcn_mfma_f32_16x16x32_bf16(pa[fm][0], vb0[fn], o[fm][fn], 0, 0, 0);
        o[fm][fn] = __builtin_amdgcn_mfma_f32_16x16x32_bf16(pa[fm][1], vb1[fn], o[fm][fn], 0, 0, 0);
      }
  }

  const int b = bh >> 3, h = bh & 7;
#pragma unroll
  for (int fm = 0; fm < 2; ++fm) {
    // lane holds partial denom for q = fm*16+lq over its 16 keys -> sum quads
    float sum = lr[fm];
    sum += __shfl_xor(sum, 16, 64);
    sum += __shfl_xor(sum, 32, 64);
    const int qbase = qt * 128 + w * 32 + fm * 16;
    if (quad == 0) pl[(size_t)kh * 32768 + bh * kN + qbase + lq] = sum;
#pragma unroll
    for (int r = 0; r < 4; ++r) {
      const size_t ob = ((size_t)kh * kTok + b * kN + qbase + quad * 4 + r) * kDim + h * 64;
#pragma unroll
      for (int fn = 0; fn < 4; ++fn) po[ob + fn * 16 + lq] = (__bf16)o[fm][fn][r];
    }
  }
}

// ===== combine thirds: ao = (sum o_kh)/(sum l_kh), bf16 ====================
__global__ __launch_bounds__(256) void combine(const __bf16* __restrict__ po,
                                               const float* __restrict__ pl,
                                               __bf16* __restrict__ ao) {
  const size_t i = ((size_t)blockIdx.x * 256 + threadIdx.x) * 4;
  const int tok = (int)(i >> 9), dk = (int)(i & 511);
  const int h = dk >> 6, b = tok >> 11, qrow = tok & (kN - 1);
  const int idx = (b * kH + h) * kN + qrow;
  float l = 0.f;
#pragma unroll
  for (int kh = 0; kh < kKH; ++kh) l += pl[kh * 32768 + idx];
  const float inv = 1.f / l;
  float s0 = 0.f, s1 = 0.f, s2 = 0.f, s3 = 0.f;
#pragma unroll
  for (int kh = 0; kh < kKH; ++kh) {
    bf16x4 a = *(const bf16x4*)(po + (size_t)kh * kTok * kDim + i);
    s0 += (float)a[0]; s1 += (float)a[1]; s2 += (float)a[2]; s3 += (float)a[3];
  }
  bf16x4 t = {(__bf16)(s0 * inv), (__bf16)(s1 * inv),
              (__bf16)(s2 * inv), (__bf16)(s3 * inv)};
  *(bf16x4*)(ao + i) = t;
}

// ===== out-proj GEMM: C[M,512] = A*B^T, 64x64 tile =========================
__global__ __launch_bounds__(256, 2) void gemm64(const __bf16* __restrict__ A,
                                                 const __bf16* __restrict__ B,
                                                 float* __restrict__ C,
                                                 int N, int K) {
  const int tid = threadIdx.x;
  const int w = tid >> 6, lane = tid & 63, quad = lane >> 4, lq = lane & 15;
  const int m0 = blockIdx.y * 64;
  const int n0 = blockIdx.x * 64;
  const int wm = (w >> 1) * 32, wn = (w & 1) * 32;
  __shared__ __bf16 As[2][4096];
  __shared__ __bf16 Bs[2][4096];

  const f32x4 zero = {0.f, 0.f, 0.f, 0.f};
  f32x4 acc00 = zero, acc01 = zero, acc10 = zero, acc11 = zero;

  const int sr = tid >> 3, ch = tid & 7;
  auto stage = [&](int k0, int buf) {
#pragma unroll
    for (int j = 0; j < 2; ++j) {
      const int row = j * 32 + sr;
      const int src = k0 + ((ch ^ (row & 7)) << 3);
      gld16(A + (size_t)(m0 + row) * K + src, &As[buf][row * 64 + ch * 8]);
      gld16(B + (size_t)(n0 + row) * K + src, &Bs[buf][row * 64 + ch * 8]);
    }
  };
  const int sw0 = ((quad ^ (lq & 7)) << 3);
  const int sw1 = (((4 | quad) ^ (lq & 7)) << 3);

  stage(0, 0);
  const int iters = K >> 6;
  for (int i = 0; i < iters; ++i) {
    __syncthreads();
    if (i + 1 < iters) stage((i + 1) << 6, (i + 1) & 1);
    const __bf16* as = As[i & 1];
    const __bf16* bs = Bs[i & 1];
#pragma unroll
    for (int ks = 0; ks < 2; ++ks) {
      const int sw = ks ? sw1 : sw0;
      bf16x8 a0 = *(const bf16x8*)&as[(wm +      lq) * 64 + sw];
      bf16x8 a1 = *(const bf16x8*)&as[(wm + 16 + lq) * 64 + sw];
      bf16x8 b0 = *(const bf16x8*)&bs[(wn +      lq) * 64 + sw];
      bf16x8 b1 = *(const bf16x8*)&bs[(wn + 16 + lq) * 64 + sw];
      acc00 = __builtin_amdgcn_mfma_f32_16x16x32_bf16(a0, b0, acc00, 0, 0, 0);
      acc01 = __builtin_amdgcn_mfma_f32_16x16x32_bf16(a0, b1, acc01, 0, 0, 0);
      acc10 = __builtin_amdgcn_mfma_f32_16x16x32_bf16(a1, b0, acc10, 0, 0, 0);
      acc11 = __builtin_amdgcn_mfma_f32_16x16x32_bf16(a1, b1, acc11, 0, 0, 0);
    }
  }
  const f32x4 av[2][2] = {{acc00, acc01}, {acc10, acc11}};
#pragma unroll
  for (int fm = 0; fm < 2; ++fm)
#pragma unroll
    for (int fn = 0; fn < 2; ++fn)
#pragma unroll
      for (int r = 0; r < 4; ++r)
        C[(size_t)(m0 + wm + fm * 16 + quad * 4 + r) * N + (n0 + wn + fn * 16 + lq)] =
            av[fm][fn][r];
}

// ===========================================================================
extern "C" void kernel_launch(void* const* d_in, const int* in_sizes, int n_in,
                              void* d_out, int out_size, void* d_ws, size_t ws_size,
                              hipStream_t stream) {
  const float* x    = (const float*)d_in[0];
  const float* Wq   = (const float*)d_in[1];
  const float* Wkv  = (const float*)d_in[2];
  const float* Wout = (const float*)d_in[3];
  float* out = (float*)d_out;
  char* ws = (char*)d_ws;

  __bf16* xb    = (__bf16*)(ws);                       //  0..4M   [4096,512]
  __bf16* wqkvb = (__bf16*)(ws + (size_t)(4 << 20));   //  4..5.5M [1536,512]
  __bf16* wob   = (__bf16*)(ws + (size_t)(6 << 20));   //  6..6.5M [512,512]
  __bf16* qn    = (__bf16*)(ws + (size_t)(7 << 20));   //  7..11M  [bh][n][d]
  __bf16* kn    = (__bf16*)(ws + (size_t)(11 << 20));  // 11..15M  [bh][n][d]
  __bf16* vt2   = (__bf16*)(ws + (size_t)(15 << 20));  // 15..19M  tiled V^T
  __bf16* po    = (__bf16*)(ws + (size_t)(19 << 20));  // 19..31M  partials x3
  float*  pl    = (float*)(ws + (size_t)(32 << 20));   // 32..32.4M
  __bf16* ao    = (__bf16*)(ws + (size_t)(33 << 20));  // 33..37M  [tok][dim]

  cvt_all<<<1536, 256, 0, stream>>>(x, Wq, Wkv, Wout, xb, wqkvb, wob);
  gemm_qkv<<<768, 256, 0, stream>>>(xb, wqkvb, qn, kn, vt2);
  attn<<<768, 256, 0, stream>>>(qn, kn, vt2, po, pl);
  combine<<<kTok * kDim / 1024, 256, 0, stream>>>(po, pl, ao);
  gemm64<<<dim3(kDim / 64, kTok / 64), 256, 0, stream>>>(ao, wob, out, kDim, kDim);
}

// Round 10
// 112.250 us; speedup vs baseline: 1.1161x; 1.0261x over previous
//
#include <hip/hip_runtime.h>

typedef __bf16 bf16x8 __attribute__((ext_vector_type(8)));
typedef __bf16 bf16x4 __attribute__((ext_vector_type(4)));
typedef __bf16 bf16x2 __attribute__((ext_vector_type(2)));
typedef float  f32x4  __attribute__((ext_vector_type(4)));
typedef unsigned int u32x2 __attribute__((ext_vector_type(2)));
typedef unsigned int u32x4 __attribute__((ext_vector_type(4)));

#define LOG2E_F 1.44269504088896340736f

static constexpr int kB = 2, kN = 2048, kH = 8, kD = 64, kDim = 512;
static constexpr int kTok = kB * kN;   // 4096
static constexpr int kNQKV = 1536;     // fused Wq(512)+Wkv(1024) rows
static constexpr int kKH = 3;          // attention split-K: 11/11/10 kt tiles

__device__ __forceinline__ void gld16(const void* g, void* l) {
  __builtin_amdgcn_global_load_lds(
      (const __attribute__((address_space(1))) void*)g,
      (__attribute__((address_space(3))) void*)l, 16, 0, 0);
}

__device__ __forceinline__ unsigned pkbf(float a, float b) {
  bf16x2 v; v[0] = (__bf16)a; v[1] = (__bf16)b;
  return __builtin_bit_cast(unsigned, v);
}

// XOR-swizzled LDS tiles (rows of 64 bf16 = 8 chunks of 16B):
// LDS chunk c of row r holds GLOBAL chunk c^(r&7). Staged via per-lane source
// permutation (gld16 dest stays lane-linear); readers XOR their chunk index
// with (row&7). Spreads quad-group b128 reads over all 32 banks.
//
// T1 XCD remap: attn/gemm_qkv (R9-verified) and now gemm64 launch 1-D with
// bijective swz = (bid&7)*chunk + bid/8 so each XCD owns contiguous work
// sharing operand panels. Pure index remap, no numerics.

// ===== fp32 -> bf16 linear converts: x | Wq | Wkv (fused) | Wout ===========
__global__ __launch_bounds__(256) void cvt_all(const float* __restrict__ x,
                                               const float* __restrict__ wq,
                                               const float* __restrict__ wkv,
                                               const float* __restrict__ wo,
                                               __bf16* __restrict__ xb,
                                               __bf16* __restrict__ wqkvb,
                                               __bf16* __restrict__ wob) {
  size_t i = ((size_t)blockIdx.x * 256 + threadIdx.x) * 8;
  const float* s; __bf16* d; size_t off;
  if (i < 2097152)      { s = x;   d = xb;              off = i; }
  else if (i < 2359296) { s = wq;  d = wqkvb;           off = i - 2097152; }
  else if (i < 2883584) { s = wkv; d = wqkvb + 262144;  off = i - 2359296; }
  else                  { s = wo;  d = wob;             off = i - 2883584; }
  float4 u = *(const float4*)(s + off);
  float4 v = *(const float4*)(s + off + 4);
  bf16x8 t;
  t[0] = (__bf16)u.x; t[1] = (__bf16)u.y; t[2] = (__bf16)u.z; t[3] = (__bf16)u.w;
  t[4] = (__bf16)v.x; t[5] = (__bf16)v.y; t[6] = (__bf16)v.z; t[7] = (__bf16)v.w;
  *(bf16x8*)(d + off) = t;
}

// ===== QKV GEMM with fused norm/transpose epilogue =========================
__global__ __launch_bounds__(256, 3) void gemm_qkv(const __bf16* __restrict__ A,
                                                   const __bf16* __restrict__ B,
                                                   __bf16* __restrict__ qn,
                                                   __bf16* __restrict__ kn,
                                                   __bf16* __restrict__ vt2) {
  const int K = kDim;
  const int tid = threadIdx.x;
  const int w = tid >> 6, lane = tid & 63, quad = lane >> 4, lq = lane & 15;
  // T1: XCD k owns swz in [96k, 96k+96) = 4 m-panels x all 24 n-tiles
  const int bid = blockIdx.x;
  const int swz = (bid & 7) * 96 + (bid >> 3);
  const int m0 = (swz / 24) * 128;
  const int n0 = (swz % 24) * 64;
  const int wm = w * 32;
  __shared__ __bf16 As[2][128 * 64];
  __shared__ __bf16 Bs[2][64 * 64];

  const f32x4 zero = {0.f, 0.f, 0.f, 0.f};
  f32x4 acc[2][4];
#pragma unroll
  for (int fm = 0; fm < 2; ++fm)
#pragma unroll
    for (int fn = 0; fn < 4; ++fn) acc[fm][fn] = zero;

  const int sr = tid >> 3, ch = tid & 7;
  auto stage = [&](int k0, int buf) {
#pragma unroll
    for (int j = 0; j < 4; ++j) {
      const int row = j * 32 + sr;
      gld16(A + (size_t)(m0 + row) * K + k0 + ((ch ^ (row & 7)) << 3),
            &As[buf][row * 64 + ch * 8]);
    }
#pragma unroll
    for (int j = 0; j < 2; ++j) {
      const int row = j * 32 + sr;
      gld16(B + (size_t)(n0 + row) * K + k0 + ((ch ^ (row & 7)) << 3),
            &Bs[buf][row * 64 + ch * 8]);
    }
  };
  const int sw0 = ((quad ^ (lq & 7)) << 3);        // ks=0
  const int sw1 = (((4 | quad) ^ (lq & 7)) << 3);  // ks=1

  stage(0, 0);
  for (int i = 0; i < 8; ++i) {
    __syncthreads();
    if (i + 1 < 8) stage((i + 1) << 6, (i + 1) & 1);
    const __bf16* as = As[i & 1];
    const __bf16* bs = Bs[i & 1];
#pragma unroll
    for (int ks = 0; ks < 2; ++ks) {
      const int sw = ks ? sw1 : sw0;
      bf16x8 a[2], b[4];
#pragma unroll
      for (int fm = 0; fm < 2; ++fm)
        a[fm] = *(const bf16x8*)&as[(wm + fm * 16 + lq) * 64 + sw];
#pragma unroll
      for (int fn = 0; fn < 4; ++fn)
        b[fn] = *(const bf16x8*)&bs[(fn * 16 + lq) * 64 + sw];
#pragma unroll
      for (int fm = 0; fm < 2; ++fm)
#pragma unroll
        for (int fn = 0; fn < 4; ++fn)
          acc[fm][fn] =
              __builtin_amdgcn_mfma_f32_16x16x32_bf16(a[fm], b[fn], acc[fm][fn], 0, 0, 0);
    }
  }

  const int h = (n0 >> 6) & 7;
  if (n0 >= 1024) {
    // ---- V: transpose via LDS (reuse As), then coalesced 16B stores ----
    __syncthreads();
    __bf16* Ts = &As[0][0];  // [2 tiles][64 d][stride 72]
#pragma unroll
    for (int fm = 0; fm < 2; ++fm)
#pragma unroll
      for (int r = 0; r < 4; ++r) {
        const int mo = wm + fm * 16 + quad * 4 + r;
        const int tau = mo >> 6, tt = mo & 63;
        const int p = (tt & 15) * 4 + (tt >> 4);  // inverse of attn's pi
#pragma unroll
        for (int fn = 0; fn < 4; ++fn)
          Ts[tau * 4608 + (fn * 16 + lq) * 72 + p] = (__bf16)acc[fm][fn][r];
      }
    __syncthreads();
    const int b = m0 >> 11, kt0 = (m0 & (kN - 1)) >> 6;
    const int dd = tid >> 2, p0 = (tid & 3) << 4;
#pragma unroll
    for (int tau = 0; tau < 2; ++tau) {
      const __bf16* src = Ts + tau * 4608 + dd * 72 + p0;
      __bf16* dst = vt2 + ((size_t)((b * kH + h) * 32 + kt0 + tau)) * 4096 + tid * 16;
      *(bf16x8*)dst = *(const bf16x8*)src;
      *(bf16x8*)(dst + 8) = *(const bf16x8*)(src + 8);
    }
  } else {
    // ---- Q/K: rms over the 64 cols ----
    const float qs = (n0 < 512) ? (0.125f * LOG2E_F) : 1.0f;
    __bf16* dst0 = (n0 < 512) ? qn : kn;
#pragma unroll
    for (int fm = 0; fm < 2; ++fm)
#pragma unroll
      for (int r = 0; r < 4; ++r) {
        float ss = 0.f;
#pragma unroll
        for (int fn = 0; fn < 4; ++fn) ss += acc[fm][fn][r] * acc[fm][fn][r];
#pragma unroll
        for (int off = 1; off < 16; off <<= 1) ss += __shfl_xor(ss, off, 64);
        const float inv = qs / (sqrtf(ss * (1.f / 64)) + 1e-4f);
        const int m = m0 + wm + fm * 16 + quad * 4 + r;
        const int b = m >> 11, n = m & (kN - 1);
        __bf16* dst = dst0 + ((size_t)(b * kH + h) * kN + n) * kD;
#pragma unroll
        for (int fn = 0; fn < 4; ++fn)
          dst[fn * 16 + lq] = (__bf16)(acc[fm][fn][r] * inv);
      }
  }
}

// ===== fused attention: block = (128-q tile, bh, key-third) ================
// R9 structure (split-K3 11/11/10, in-register permlane softmax, (256,3),
// T1 XCD remap: XCD k owns 6 complete (bh,kh) K/V sets).
// Softmax IN-REGISTER via swapped QK^T (S^T = mfma(K,Q)); permlane
// redistribution verified R6/R8. Fixed-max softmax (|s| <= 11.54 < 12).
__global__ __launch_bounds__(256, 3) void attn(const __bf16* __restrict__ qn,
                                               const __bf16* __restrict__ kn,
                                               const __bf16* __restrict__ vt2,
                                               __bf16* __restrict__ po,
                                               float* __restrict__ pl) {
  const int bid = blockIdx.x;
  const int swz = (bid & 7) * 96 + (bid >> 3);   // bijective: 768 = 96*8
  const int qt = swz & 15, bhkh = swz >> 4;
  const int bh = bhkh & 15, kh = bhkh >> 4;
  const int kt0 = kh * 11;
  const int cnt = (kh == 2) ? 10 : 11;
  const int tid = threadIdx.x;
  const int w = tid >> 6, lane = tid & 63, quad = lane >> 4, lq = lane & 15;
  __shared__ __bf16 Ks[2][4096];
  __shared__ __bf16 Vs[2][4096];

  bf16x8 aq[2][2];
#pragma unroll
  for (int fm = 0; fm < 2; ++fm) {
    const __bf16* Qb = qn + ((size_t)bh * kN + qt * 128 + w * 32 + fm * 16 + lq) * kD;
    aq[fm][0] = *(const bf16x8*)(Qb + quad * 8);
    aq[fm][1] = *(const bf16x8*)(Qb + 32 + quad * 8);
  }

  const f32x4 zero  = {0.f, 0.f, 0.f, 0.f};
  const f32x4 minit = {-12.f, -12.f, -12.f, -12.f};
  f32x4 o[2][4];
  float lr[2] = {0.f, 0.f};
#pragma unroll
  for (int fm = 0; fm < 2; ++fm)
#pragma unroll
    for (int i = 0; i < 4; ++i) o[fm][i] = zero;

  const __bf16* Kb = kn + (size_t)bh * kN * kD;   // tile ktg at +ktg*4096
  const __bf16* Vb = vt2 + (size_t)bh * 32 * 4096;

  auto stage = [&](int ktg, int buf) {
#pragma unroll
    for (int j = 0; j < 2; ++j) {
      const int s = j * 256 + tid;
      const int row = s >> 3, ch = s & 7;
      const int src = row * 64 + ((ch ^ (row & 7)) << 3);
      gld16(Kb + (size_t)ktg * 4096 + src, &Ks[buf][s * 8]);
      gld16(Vb + (size_t)ktg * 4096 + src, &Vs[buf][s * 8]);
    }
  };
  const int sw0 = ((quad ^ (lq & 7)) << 3);
  const int sw1 = (((4 | quad) ^ (lq & 7)) << 3);

  stage(kt0, 0);
  for (int kt = 0; kt < cnt; ++kt) {
    __syncthreads();
    if (kt + 1 < cnt) stage(kt0 + kt + 1, (kt + 1) & 1);
    const __bf16* ks_ = Ks[kt & 1];
    const __bf16* vs_ = Vs[kt & 1];

    bf16x8 kb0[4], kb1[4];
#pragma unroll
    for (int fn = 0; fn < 4; ++fn) {
      const int rb = (fn * 16 + lq) * 64;
      kb0[fn] = *(const bf16x8*)&ks_[rb + sw0];
      kb1[fn] = *(const bf16x8*)&ks_[rb + sw1];
    }

    bf16x8 pa[2][2];
#pragma unroll
    for (int fm = 0; fm < 2; ++fm) {
      // S^T = K·Q^T (+ -12 bias): lane -> q=lq, key=fn*16+quad*4+r
      f32x4 s[4];
#pragma unroll
      for (int fn = 0; fn < 4; ++fn) {
        f32x4 a = __builtin_amdgcn_mfma_f32_16x16x32_bf16(kb0[fn], aq[fm][0], minit, 0, 0, 0);
        s[fn] = __builtin_amdgcn_mfma_f32_16x16x32_bf16(kb1[fn], aq[fm][1], a, 0, 0, 0);
      }
      float p[4][4];
      float ls = 0.f;
#pragma unroll
      for (int fn = 0; fn < 4; ++fn)
#pragma unroll
        for (int r = 0; r < 4; ++r) {
          p[fn][r] = __builtin_amdgcn_exp2f(s[fn][r]);
          ls += p[fn][r];
        }
      lr[fm] += ls;
      unsigned Wp[2][4];
#pragma unroll
      for (int j = 0; j < 2; ++j)
#pragma unroll
        for (int r = 0; r < 4; ++r) Wp[j][r] = pkbf(p[2 * j][r], p[2 * j + 1][r]);
      unsigned pw[2][4];
#pragma unroll
      for (int wi = 0; wi < 4; ++wi) {
        const int j = wi & 1, dl = wi >> 1;
        u32x2 t1 = __builtin_amdgcn_permlane16_swap(Wp[j][dl], Wp[j][2 + dl], false, false);
        u32x2 t2 = __builtin_amdgcn_permlane32_swap(t1[0], t1[1], false, false);
        pw[0][wi] = t2[0]; pw[1][wi] = t2[1];
      }
#pragma unroll
      for (int ks = 0; ks < 2; ++ks) {
        u32x4 pv = {pw[ks][0], pw[ks][1], pw[ks][2], pw[ks][3]};
        pa[fm][ks] = __builtin_bit_cast(bf16x8, pv);
      }
    }

    bf16x8 vb0[4], vb1[4];
#pragma unroll
    for (int fn = 0; fn < 4; ++fn) {
      const int rb = (fn * 16 + lq) * 64;
      vb0[fn] = *(const bf16x8*)&vs_[rb + sw0];
      vb1[fn] = *(const bf16x8*)&vs_[rb + sw1];
    }
#pragma unroll
    for (int fm = 0; fm < 2; ++fm)
#pragma unroll
      for (int fn = 0; fn < 4; ++fn) {
        o[fm][fn] = __builtin_amdgcn_mfma_f32_16x16x32_bf16(pa[fm][0], vb0[fn], o[fm][fn], 0, 0, 0);
        o[fm][fn] = __builtin_amdgcn_mfma_f32_16x16x32_bf16(pa[fm][1], vb1[fn], o[fm][fn], 0, 0, 0);
      }
  }

  const int b = bh >> 3, h = bh & 7;
#pragma unroll
  for (int fm = 0; fm < 2; ++fm) {
    // lane holds partial denom for q = fm*16+lq over its 16 keys -> sum quads
    float sum = lr[fm];
    sum += __shfl_xor(sum, 16, 64);
    sum += __shfl_xor(sum, 32, 64);
    const int qbase = qt * 128 + w * 32 + fm * 16;
    if (quad == 0) pl[(size_t)kh * 32768 + bh * kN + qbase + lq] = sum;
#pragma unroll
    for (int r = 0; r < 4; ++r) {
      const size_t ob = ((size_t)kh * kTok + b * kN + qbase + quad * 4 + r) * kDim + h * 64;
#pragma unroll
      for (int fn = 0; fn < 4; ++fn) po[ob + fn * 16 + lq] = (__bf16)o[fm][fn][r];
    }
  }
}

// ===== combine thirds: ao = (sum o_kh)/(sum l_kh), bf16 (x8 vectorized) ====
__global__ __launch_bounds__(256) void combine(const __bf16* __restrict__ po,
                                               const float* __restrict__ pl,
                                               __bf16* __restrict__ ao) {
  const size_t i = ((size_t)blockIdx.x * 256 + threadIdx.x) * 8;
  const int tok = (int)(i >> 9), dk = (int)(i & 511);
  const int h = dk >> 6, b = tok >> 11, qrow = tok & (kN - 1);
  const int idx = (b * kH + h) * kN + qrow;
  float l = 0.f;
#pragma unroll
  for (int kh = 0; kh < kKH; ++kh) l += pl[kh * 32768 + idx];
  const float inv = 1.f / l;
  float s[8] = {0.f, 0.f, 0.f, 0.f, 0.f, 0.f, 0.f, 0.f};
#pragma unroll
  for (int kh = 0; kh < kKH; ++kh) {
    bf16x8 a = *(const bf16x8*)(po + (size_t)kh * kTok * kDim + i);
#pragma unroll
    for (int e = 0; e < 8; ++e) s[e] += (float)a[e];
  }
  bf16x8 t;
#pragma unroll
  for (int e = 0; e < 8; ++e) t[e] = (__bf16)(s[e] * inv);
  *(bf16x8*)(ao + i) = t;
}

// ===== out-proj GEMM: C[M,512] = A*B^T, 64x64 tile, T1 XCD remap ===========
__global__ __launch_bounds__(256, 2) void gemm64(const __bf16* __restrict__ A,
                                                 const __bf16* __restrict__ B,
                                                 float* __restrict__ C,
                                                 int N, int K) {
  const int tid = threadIdx.x;
  const int w = tid >> 6, lane = tid & 63, quad = lane >> 4, lq = lane & 15;
  // T1: 512 = 64 x 8; XCD k owns 8 consecutive m-panels x all 8 n-tiles
  // (A working set 512 KB in its L2; Wout 0.5 MB L2-resident everywhere).
  const int bid = blockIdx.x;
  const int swz = (bid & 7) * 64 + (bid >> 3);
  const int m0 = (swz >> 3) * 64;
  const int n0 = (swz & 7) * 64;
  const int wm = (w >> 1) * 32, wn = (w & 1) * 32;
  __shared__ __bf16 As[2][4096];
  __shared__ __bf16 Bs[2][4096];

  const f32x4 zero = {0.f, 0.f, 0.f, 0.f};
  f32x4 acc00 = zero, acc01 = zero, acc10 = zero, acc11 = zero;

  const int sr = tid >> 3, ch = tid & 7;
  auto stage = [&](int k0, int buf) {
#pragma unroll
    for (int j = 0; j < 2; ++j) {
      const int row = j * 32 + sr;
      const int src = k0 + ((ch ^ (row & 7)) << 3);
      gld16(A + (size_t)(m0 + row) * K + src, &As[buf][row * 64 + ch * 8]);
      gld16(B + (size_t)(n0 + row) * K + src, &Bs[buf][row * 64 + ch * 8]);
    }
  };
  const int sw0 = ((quad ^ (lq & 7)) << 3);
  const int sw1 = (((4 | quad) ^ (lq & 7)) << 3);

  stage(0, 0);
  const int iters = K >> 6;
  for (int i = 0; i < iters; ++i) {
    __syncthreads();
    if (i + 1 < iters) stage((i + 1) << 6, (i + 1) & 1);
    const __bf16* as = As[i & 1];
    const __bf16* bs = Bs[i & 1];
#pragma unroll
    for (int ks = 0; ks < 2; ++ks) {
      const int sw = ks ? sw1 : sw0;
      bf16x8 a0 = *(const bf16x8*)&as[(wm +      lq) * 64 + sw];
      bf16x8 a1 = *(const bf16x8*)&as[(wm + 16 + lq) * 64 + sw];
      bf16x8 b0 = *(const bf16x8*)&bs[(wn +      lq) * 64 + sw];
      bf16x8 b1 = *(const bf16x8*)&bs[(wn + 16 + lq) * 64 + sw];
      acc00 = __builtin_amdgcn_mfma_f32_16x16x32_bf16(a0, b0, acc00, 0, 0, 0);
      acc01 = __builtin_amdgcn_mfma_f32_16x16x32_bf16(a0, b1, acc01, 0, 0, 0);
      acc10 = __builtin_amdgcn_mfma_f32_16x16x32_bf16(a1, b0, acc10, 0, 0, 0);
      acc11 = __builtin_amdgcn_mfma_f32_16x16x32_bf16(a1, b1, acc11, 0, 0, 0);
    }
  }
  const f32x4 av[2][2] = {{acc00, acc01}, {acc10, acc11}};
#pragma unroll
  for (int fm = 0; fm < 2; ++fm)
#pragma unroll
    for (int fn = 0; fn < 2; ++fn)
#pragma unroll
      for (int r = 0; r < 4; ++r)
        C[(size_t)(m0 + wm + fm * 16 + quad * 4 + r) * N + (n0 + wn + fn * 16 + lq)] =
            av[fm][fn][r];
}

// ===========================================================================
extern "C" void kernel_launch(void* const* d_in, const int* in_sizes, int n_in,
                              void* d_out, int out_size, void* d_ws, size_t ws_size,
                              hipStream_t stream) {
  const float* x    = (const float*)d_in[0];
  const float* Wq   = (const float*)d_in[1];
  const float* Wkv  = (const float*)d_in[2];
  const float* Wout = (const float*)d_in[3];
  float* out = (float*)d_out;
  char* ws = (char*)d_ws;

  __bf16* xb    = (__bf16*)(ws);                       //  0..4M   [4096,512]
  __bf16* wqkvb = (__bf16*)(ws + (size_t)(4 << 20));   //  4..5.5M [1536,512]
  __bf16* wob   = (__bf16*)(ws + (size_t)(6 << 20));   //  6..6.5M [512,512]
  __bf16* qn    = (__bf16*)(ws + (size_t)(7 << 20));   //  7..11M  [bh][n][d]
  __bf16* kn    = (__bf16*)(ws + (size_t)(11 << 20));  // 11..15M  [bh][n][d]
  __bf16* vt2   = (__bf16*)(ws + (size_t)(15 << 20));  // 15..19M  tiled V^T
  __bf16* po    = (__bf16*)(ws + (size_t)(19 << 20));  // 19..31M  partials x3
  float*  pl    = (float*)(ws + (size_t)(32 << 20));   // 32..32.4M
  __bf16* ao    = (__bf16*)(ws + (size_t)(33 << 20));  // 33..37M  [tok][dim]

  cvt_all<<<1536, 256, 0, stream>>>(x, Wq, Wkv, Wout, xb, wqkvb, wob);
  gemm_qkv<<<768, 256, 0, stream>>>(xb, wqkvb, qn, kn, vt2);
  attn<<<768, 256, 0, stream>>>(qn, kn, vt2, po, pl);
  combine<<<kTok * kDim / 2048, 256, 0, stream>>>(po, pl, ao);
  gemm64<<<512, 256, 0, stream>>>(ao, wob, out, kDim, kDim);
}